// Round 9
// baseline (512.491 us; speedup 1.0000x reference)
//
#include <hip/hip_runtime.h>

typedef unsigned int   u32;
typedef unsigned short u16;
typedef __bf16 bf16x8 __attribute__((ext_vector_type(8)));
typedef float  f32x4  __attribute__((ext_vector_type(4)));

__device__ __forceinline__ u16 f2bf(float f) {
    u32 u = __builtin_bit_cast(u32, f);
    u += 0x7FFFu + ((u >> 16) & 1u);
    return (u16)(u >> 16);
}
__device__ __forceinline__ u32 pk2bf(float a, float b) {
    return (u32)f2bf(a) | ((u32)f2bf(b) << 16);
}
__device__ __forceinline__ bf16x8 ldfrag(const u16* p) {
    return __builtin_bit_cast(bf16x8, *reinterpret_cast<const uint4*>(p));
}

// bank-conflict swizzle on the 16B-chunk index (0..63): fold bits[5:3] into [2:0].
__device__ __forceinline__ u32 swz(u32 i) { return i ^ ((i >> 3) & 7u); }

// LDS-only barrier: does NOT drain vmcnt, so register prefetch loads survive.
// (All cross-wave deps in this kernel are through LDS; __syncthreads would
// drain vmcnt(0) and kill the pipeline — m97 evidence.)
__device__ __forceinline__ void bar_lds() {
    asm volatile("s_waitcnt lgkmcnt(0)" ::: "memory");
    __builtin_amdgcn_s_barrier();
    __builtin_amdgcn_sched_barrier(0);
}

// ---------------------------------------------------------------------------
// Fused Swin branch: LN -> QKV -> windowed MHA -> proj -> +residual
// WG = 768 threads = 12 waves = TWO independent windows (R7 structure:
// balanced 3 waves/SIMD; 6-wave WGs place (2,2,1,1) and a 2nd WG never fits
// at our ~140-reg footprint — R8's forced 128-cap spilled 180MB).
// PERSISTENT: grid 256, each WG processes 4 window-pairs. Next pair's x
// (8 float4/thread) is prefetched right after the yln barrier and consumed
// next iteration -> the 49KB/window gather overlaps phases 2-4. Residual x
// re-read hoisted into phase 3 (L2-hot, hides under PV+proj).
// Per-window LDS partition (u16, base = win*24576):
//   [0,12288)      yln frag blocks; phase 3: wave w's own blocks {s*6+w} =
//                  scratch for k -> V^T -> attn_out (wave-local, DS in-order)
//   [12288,24576)  qreg per-head q A-frags; P staging reuses it after QK^T.
// ---------------------------------------------------------------------------
template<int SHIFT>
__global__ __launch_bounds__(768) void swin_branch(
    const float* __restrict__ xin, float* __restrict__ xout,
    const float* __restrict__ ln_g, const float* __restrict__ ln_b,
    const u16*   __restrict__ wqkv_t,  // [576][192] bf16 (pre-transposed)
    const float* __restrict__ qkv_b,   // [576]
    const u16*   __restrict__ wproj_t, // [192][192] bf16 (pre-transposed)
    const float* __restrict__ proj_b)  // [192]
{
    __shared__ __align__(16) u16 smem[49152];
    __shared__ float red1[2][6][64];
    __shared__ float red2[2][6][64];
    constexpr u32 QOFF = 12288;

    const int tid  = threadIdx.x;
    const int win  = (tid >= 384) ? 1 : 0;
    const int lt   = tid - win*384;
    const int wid  = lt >> 6;               // wave == head
    const int lane = lt & 63;
    const int lr   = lane & 15;
    const int lg   = lane >> 4;
    const u32 lsw  = swz((u32)lane);
    const u32 SB   = (u32)win * 24576u;

    const int ty = lane >> 3, tx = lane & 7;

    // prologue: load iteration-0 window x
    float4 xv4[8];
    {
        const int Wid = (int)blockIdx.x*2 + win;
        const int b=Wid>>8, wy=(Wid>>4)&15, wx=Wid&15;
        const int shy=(wy*8+ty+SHIFT)&127, shx=(wx*8+tx+SHIFT)&127;
        const float* xp = xin + ((size_t)((b*128+shy)*128+shx))*192 + wid*32;
        #pragma unroll
        for (int j=0;j<8;++j) xv4[j] = reinterpret_cast<const float4*>(xp)[j];
    }

    #pragma unroll 1
    for (int it = 0; it < 4; ++it) {
        const int Wid = (it*256 + (int)blockIdx.x)*2 + win;
        const int b   = Wid >> 8;
        const int wy  = (Wid >> 4) & 15;
        const int wx  = Wid & 15;

        if (it) bar_lds();   // prev iteration's proj finished reading yln area

        // ---- Phase 1: LayerNorm from xv4 -> yln (A-frag layout) ----
        {
            float s1=0.f, s2=0.f;
            #pragma unroll
            for (int j=0;j<8;++j) {
                float4 v = xv4[j];
                s1 += v.x+v.y+v.z+v.w;
                s2 += v.x*v.x+v.y*v.y+v.z*v.z+v.w*v.w;
            }
            red1[win][wid][lane]=s1; red2[win][wid][lane]=s2;
        }
        bar_lds();
        {
            float a1=0.f, a2s=0.f;
            #pragma unroll
            for (int w=0;w<6;++w){ a1+=red1[win][w][lane]; a2s+=red2[win][w][lane]; }
            const float mu = a1*(1.f/192.f);
            const float rs = rsqrtf(a2s*(1.f/192.f)-mu*mu+1e-5f);
            const float* gp = ln_g + wid*32;
            const float* bp = ln_b + wid*32;
            const float* xf = reinterpret_cast<const float*>(xv4);
            const u32 yblk = SB + (u32)((lg*6+wid)*512);
            #pragma unroll
            for (int cc8=0; cc8<4; ++cc8) {
                u32 pk[4];
                #pragma unroll
                for (int q=0;q<4;++q){
                    int j=cc8*8+q*2;
                    float y0=(xf[j]  -mu)*rs*gp[j]  +bp[j];
                    float y1=(xf[j+1]-mu)*rs*gp[j+1]+bp[j+1];
                    pk[q]=pk2bf(y0,y1);
                }
                *reinterpret_cast<uint4*>(&smem[yblk + swz((u32)(lr+16*cc8))*8]) =
                    make_uint4(pk[0],pk[1],pk[2],pk[3]);
            }
        }
        bar_lds();   // yln visible to all waves of this window

        // ---- prefetch next pair's x (loads stay in flight across barriers) ----
        float4 xn4[8];
        if (it < 3) {
            const int WidN = ((it+1)*256 + (int)blockIdx.x)*2 + win;
            const int bn=WidN>>8, wyn=(WidN>>4)&15, wxn=WidN&15;
            const int shy=(wyn*8+ty+SHIFT)&127, shx=(wxn*8+tx+SHIFT)&127;
            const float* xp = xin + ((size_t)((bn*128+shy)*128+shx))*192 + wid*32;
            #pragma unroll
            for (int j=0;j<8;++j) xn4[j] = reinterpret_cast<const float4*>(xp)[j];
        }

        // ---- Phase 2: QKV GEMM, three passes (8 accumulators each) ----
        uint2 kpk[4][2];
        uint2 vpk[4][2];
        {
            // pass q -> qreg
            {
                f32x4 acc[4][2];
                #pragma unroll
                for (int mi=0; mi<4; ++mi)
                    #pragma unroll
                    for (int t=0; t<2; ++t) acc[mi][t] = f32x4{0.f,0.f,0.f,0.f};
                #pragma unroll
                for (int ks=0; ks<6; ++ks) {
                    bf16x8 af[4];
                    #pragma unroll
                    for (int mi=0; mi<4; ++mi)
                        af[mi] = ldfrag(&smem[SB + (u32)((mi*6+ks)*512) + lsw*8]);
                    bf16x8 bw[2];
                    #pragma unroll
                    for (int t=0; t<2; ++t)
                        bw[t] = ldfrag(&wqkv_t[(wid*32 + t*16 + lr)*192 + 32*ks + 8*lg]);
                    #pragma unroll
                    for (int mi=0; mi<4; ++mi)
                        #pragma unroll
                        for (int t=0; t<2; ++t)
                            acc[mi][t] = __builtin_amdgcn_mfma_f32_16x16x32_bf16(af[mi], bw[t], acc[mi][t], 0,0,0);
                }
                #pragma unroll
                for (int t=0; t<2; ++t) {
                    const float bias = qkv_b[wid*32 + t*16 + lr];
                    const u32 lphi   = (u32)(16*(2*t + (lr>>3)));
                    #pragma unroll
                    for (int mi=0; mi<4; ++mi)
                        #pragma unroll
                        for (int rg=0; rg<4; ++rg) {
                            const u32 pos = (u32)(4*lg + rg) + lphi;
                            smem[SB + QOFF + (u32)(wid*2048) + mi*512 + swz(pos)*8 + (lr&7)] =
                                f2bf((acc[mi][t][rg] + bias) * 0.1767766952966369f);
                        }
                }
            }
            // pass k -> kpk regs
            {
                f32x4 acc[4][2];
                #pragma unroll
                for (int mi=0; mi<4; ++mi)
                    #pragma unroll
                    for (int t=0; t<2; ++t) acc[mi][t] = f32x4{0.f,0.f,0.f,0.f};
                #pragma unroll
                for (int ks=0; ks<6; ++ks) {
                    bf16x8 af[4];
                    #pragma unroll
                    for (int mi=0; mi<4; ++mi)
                        af[mi] = ldfrag(&smem[SB + (u32)((mi*6+ks)*512) + lsw*8]);
                    bf16x8 bw[2];
                    #pragma unroll
                    for (int t=0; t<2; ++t)
                        bw[t] = ldfrag(&wqkv_t[(192 + wid*32 + t*16 + lr)*192 + 32*ks + 8*lg]);
                    #pragma unroll
                    for (int mi=0; mi<4; ++mi)
                        #pragma unroll
                        for (int t=0; t<2; ++t)
                            acc[mi][t] = __builtin_amdgcn_mfma_f32_16x16x32_bf16(af[mi], bw[t], acc[mi][t], 0,0,0);
                }
                #pragma unroll
                for (int t2=0; t2<2; ++t2) {
                    const float bias = qkv_b[192 + wid*32 + t2*16 + lr];
                    #pragma unroll
                    for (int mi=0; mi<4; ++mi)
                        kpk[mi][t2] = make_uint2(
                            pk2bf(acc[mi][t2][0] + bias, acc[mi][t2][1] + bias),
                            pk2bf(acc[mi][t2][2] + bias, acc[mi][t2][3] + bias));
                }
            }
            // pass v -> vpk regs
            {
                f32x4 acc[4][2];
                #pragma unroll
                for (int mi=0; mi<4; ++mi)
                    #pragma unroll
                    for (int t=0; t<2; ++t) acc[mi][t] = f32x4{0.f,0.f,0.f,0.f};
                #pragma unroll
                for (int ks=0; ks<6; ++ks) {
                    bf16x8 af[4];
                    #pragma unroll
                    for (int mi=0; mi<4; ++mi)
                        af[mi] = ldfrag(&smem[SB + (u32)((mi*6+ks)*512) + lsw*8]);
                    bf16x8 bw[2];
                    #pragma unroll
                    for (int t=0; t<2; ++t)
                        bw[t] = ldfrag(&wqkv_t[(384 + wid*32 + t*16 + lr)*192 + 32*ks + 8*lg]);
                    #pragma unroll
                    for (int mi=0; mi<4; ++mi)
                        #pragma unroll
                        for (int t=0; t<2; ++t)
                            acc[mi][t] = __builtin_amdgcn_mfma_f32_16x16x32_bf16(af[mi], bw[t], acc[mi][t], 0,0,0);
                }
                #pragma unroll
                for (int tv=0; tv<2; ++tv) {
                    const float bias = qkv_b[384 + wid*32 + tv*16 + lr];
                    #pragma unroll
                    for (int mi=0; mi<4; ++mi)
                        vpk[mi][tv] = make_uint2(
                            pk2bf(acc[mi][tv][0] + bias, acc[mi][tv][1] + bias),
                            pk2bf(acc[mi][tv][2] + bias, acc[mi][tv][3] + bias));
                }
            }
        }
        bar_lds();   // all yln reads done -> wave's blocks {s*6+w} become scratch

        // ---- Phase 3: attention, wave-local ----
        float rsum[4][4];
        f32x4 o_[4][2];
        float resv[4][2][4];   // residual x, loaded mid-phase (L2-hot)
        {
            const u32 W  = SB + (u32)(wid*512);
            const u32 qb = SB + QOFF + (u32)(wid*2048);
            #define BLK(s) ((u32)(s)*3072u + W)

            // k scatter -> scratch blocks, read frags
            #pragma unroll
            for (int t2=0; t2<2; ++t2) {
                const u32 lphi = (u32)(16*(2*t2 + (lr>>3)));
                #pragma unroll
                for (int mi=0; mi<4; ++mi) {
                    const u32 a0 = BLK(mi) + (lr&7);
                    smem[a0 + swz((u32)(4*lg+0) + lphi)*8] = (u16)(kpk[mi][t2].x);
                    smem[a0 + swz((u32)(4*lg+1) + lphi)*8] = (u16)(kpk[mi][t2].x >> 16);
                    smem[a0 + swz((u32)(4*lg+2) + lphi)*8] = (u16)(kpk[mi][t2].y);
                    smem[a0 + swz((u32)(4*lg+3) + lphi)*8] = (u16)(kpk[mi][t2].y >> 16);
                }
            }
            bf16x8 aq[4], bk[4];
            #pragma unroll
            for (int mi=0; mi<4; ++mi) aq[mi] = ldfrag(&smem[qb + mi*512 + lsw*8]);
            #pragma unroll
            for (int ni=0; ni<4; ++ni) bk[ni] = ldfrag(&smem[BLK(ni) + lsw*8]);
            __builtin_amdgcn_sched_barrier(0);

            // V^T scatter into same scratch (k dead after bk reads; DS in-order)
            #pragma unroll
            for (int tv=0; tv<2; ++tv)
                #pragma unroll
                for (int mi=0; mi<4; ++mi) {
                    const u32 pos = (u32)(lr + 16*(2*(mi&1) + (lg>>1)));
                    *reinterpret_cast<uint2*>(
                        &smem[BLK(tv*2 + (mi>>1)) + swz(pos)*8 + 4*(lg&1)]) = vpk[mi][tv];
                }

            // per-mi QK^T + mask + softmax, pack P to bf16 immediately
            int kl[4];
            if constexpr (SHIFT > 0) {
                #pragma unroll
                for (int ni=0; ni<4; ++ni) {
                    const int col = 16*ni + lr;
                    const int hu = wy*8 + (col>>3);
                    const int wu = wx*8 + (col&7);
                    kl[ni] = ((hu >= 124) ? 2 : (hu >= 120 ? 1 : 0))*3
                           + ((wu >= 124) ? 2 : (wu >= 120 ? 1 : 0));
                }
            }
            u32 p16[4][4][2];
            #pragma unroll
            for (int mi=0; mi<4; ++mi) {
                f32x4 sr[4];
                #pragma unroll
                for (int ni=0; ni<4; ++ni)
                    sr[ni] = __builtin_amdgcn_mfma_f32_16x16x32_bf16(aq[mi], bk[ni],
                                 f32x4{0.f,0.f,0.f,0.f}, 0,0,0);
                if constexpr (SHIFT > 0) {
                    #pragma unroll
                    for (int rg=0; rg<4; ++rg) {
                        const int row = 16*mi + 4*lg + rg;
                        const int hu = wy*8 + (row>>3);
                        const int wu = wx*8 + (row&7);
                        const int rl = ((hu >= 124) ? 2 : (hu >= 120 ? 1 : 0))*3
                                     + ((wu >= 124) ? 2 : (wu >= 120 ? 1 : 0));
                        #pragma unroll
                        for (int ni=0; ni<4; ++ni)
                            if (rl != kl[ni]) sr[ni][rg] += -100.f;
                    }
                }
                #pragma unroll
                for (int rg=0; rg<4; ++rg) {
                    float m = fmaxf(fmaxf(sr[0][rg], sr[1][rg]), fmaxf(sr[2][rg], sr[3][rg]));
                    #pragma unroll
                    for (int off=1; off<16; off<<=1) m = fmaxf(m, __shfl_xor(m, off, 64));
                    float sm = 0.f;
                    #pragma unroll
                    for (int ni=0; ni<4; ++ni) {
                        float e = __expf(sr[ni][rg] - m);
                        sr[ni][rg] = e;
                        sm += e;
                    }
                    #pragma unroll
                    for (int off=1; off<16; off<<=1) sm += __shfl_xor(sm, off, 64);
                    rsum[mi][rg] = 1.0f / sm;
                }
                #pragma unroll
                for (int ni=0; ni<4; ++ni) {
                    p16[mi][ni][0] = pk2bf(sr[ni][0], sr[ni][1]);
                    p16[mi][ni][1] = pk2bf(sr[ni][2], sr[ni][3]);
                }
            }

            // P staged in two ksv halves in qreg (q dead after QK^T)
            bf16x8 ap0[4], ap1[4];
            #pragma unroll
            for (int mi=0; mi<4; ++mi)
                #pragma unroll
                for (int ni=0; ni<2; ++ni)
                    #pragma unroll
                    for (int rg=0; rg<4; ++rg) {
                        const u32 pos = (u32)(4*lg + rg + 16*(2*ni + (lr>>3)));
                        smem[qb + mi*512 + swz(pos)*8 + (lr&7)] =
                            (u16)(p16[mi][ni][rg>>1] >> (16*(rg&1)));
                    }
            #pragma unroll
            for (int mi=0; mi<4; ++mi) ap0[mi] = ldfrag(&smem[qb + mi*512 + lsw*8]);
            __builtin_amdgcn_sched_barrier(0);
            #pragma unroll
            for (int mi=0; mi<4; ++mi)
                #pragma unroll
                for (int ni=2; ni<4; ++ni)
                    #pragma unroll
                    for (int rg=0; rg<4; ++rg) {
                        const u32 pos = (u32)(4*lg + rg + 16*(2*(ni-2) + (lr>>3)));
                        smem[qb + mi*512 + swz(pos)*8 + (lr&7)] =
                            (u16)(p16[mi][ni][rg>>1] >> (16*(rg&1)));
                    }
            #pragma unroll
            for (int mi=0; mi<4; ++mi) ap1[mi] = ldfrag(&smem[qb + mi*512 + lsw*8]);
            __builtin_amdgcn_sched_barrier(0);

            // residual x loads (same addresses phase 1 just read -> L2-hot);
            // issued here so they hide under PV + attn_out + proj
            #pragma unroll
            for (int mi=0; mi<4; ++mi) {
                const int ty2 = 2*mi + (lg>>1);
                const int shy = (wy*8 + ty2 + SHIFT) & 127;
                #pragma unroll
                for (int rg=0; rg<4; ++rg) {
                    const int tx2 = 4*(lg&1) + rg;
                    const int shx = (wx*8 + tx2 + SHIFT) & 127;
                    const float* rp = xin + ((size_t)((b*128+shy)*128+shx))*192 + wid*32 + lr;
                    resv[mi][0][rg] = rp[0];
                    resv[mi][1][rg] = rp[16];
                }
            }

            bf16x8 bv[2][2];
            #pragma unroll
            for (int tv=0; tv<2; ++tv)
                #pragma unroll
                for (int ksv=0; ksv<2; ++ksv)
                    bv[tv][ksv] = ldfrag(&smem[BLK(tv*2+ksv) + lsw*8]);

            // PV
            #pragma unroll
            for (int mi=0; mi<4; ++mi)
                #pragma unroll
                for (int tv=0; tv<2; ++tv) {
                    o_[mi][tv] = __builtin_amdgcn_mfma_f32_16x16x32_bf16(ap0[mi], bv[tv][0],
                                     f32x4{0.f,0.f,0.f,0.f}, 0,0,0);
                    o_[mi][tv] = __builtin_amdgcn_mfma_f32_16x16x32_bf16(ap1[mi], bv[tv][1],
                                     o_[mi][tv], 0,0,0);
                }
            __builtin_amdgcn_sched_barrier(0);

            // normalized attn_out -> own scratch blocks (= proj A-frags ks=wid)
            #pragma unroll
            for (int mi=0; mi<4; ++mi)
                #pragma unroll
                for (int tv=0; tv<2; ++tv)
                    #pragma unroll
                    for (int rg=0; rg<4; ++rg) {
                        const u32 pos = (u32)(4*lg + rg + 16*(2*tv + (lr>>3)));
                        smem[BLK(mi) + swz(pos)*8 + (lr&7)] = f2bf(o_[mi][tv][rg] * rsum[mi][rg]);
                    }
            #undef BLK
        }
        bar_lds();   // attn_out visible

        // ---- Phase 4: proj GEMM + bias + residual(from regs) + store ----
        {
            f32x4 a2[4][2];
            #pragma unroll
            for (int mi=0; mi<4; ++mi)
                #pragma unroll
                for (int ni=0; ni<2; ++ni) a2[mi][ni] = f32x4{0.f,0.f,0.f,0.f};
            #pragma unroll
            for (int ks=0; ks<6; ++ks) {
                bf16x8 af[4], bw[2];
                #pragma unroll
                for (int mi=0; mi<4; ++mi)
                    af[mi] = ldfrag(&smem[SB + (u32)((mi*6+ks)*512) + lsw*8]);
                #pragma unroll
                for (int ni=0; ni<2; ++ni)
                    bw[ni] = ldfrag(&wproj_t[(wid*32 + 16*ni + lr)*192 + 32*ks + 8*lg]);
                #pragma unroll
                for (int mi=0; mi<4; ++mi)
                    #pragma unroll
                    for (int ni=0; ni<2; ++ni)
                        a2[mi][ni] = __builtin_amdgcn_mfma_f32_16x16x32_bf16(af[mi], bw[ni], a2[mi][ni], 0,0,0);
            }
            #pragma unroll
            for (int ni=0; ni<2; ++ni) {
                const int c  = wid*32 + 16*ni + lr;
                const float pb = proj_b[c];
                #pragma unroll
                for (int mi=0; mi<4; ++mi) {
                    const int ty2 = 2*mi + (lg>>1);
                    const int shy = (wy*8 + ty2 + SHIFT) & 127;
                    #pragma unroll
                    for (int rg=0; rg<4; ++rg) {
                        const int tx2 = 4*(lg&1) + rg;
                        const int shx = (wx*8 + tx2 + SHIFT) & 127;
                        const size_t idx = ((size_t)((b*128+shy)*128+shx))*192 + c;
                        xout[idx] = resv[mi][ni][rg] + a2[mi][ni][rg] + pb;
                    }
                }
            }
        }

        // roll prefetched x into place for next iteration
        if (it < 3) {
            #pragma unroll
            for (int j=0;j<8;++j) xv4[j] = xn4[j];
        }
    }
}

// ws layout (u16): [0) wqkv1_t 110592 | 110592) wproj1_t 36864 | 147456) wqkv2_t 110592 | 258048) wproj2_t 36864
__global__ void prep_weights(const float* __restrict__ qkv1, const float* __restrict__ proj1,
                             const float* __restrict__ qkv2, const float* __restrict__ proj2,
                             u16* __restrict__ ws)
{
    const int i = blockIdx.x*blockDim.x + threadIdx.x;
    if (i < 110592) {
        const int n = i / 192, k = i - n*192;
        ws[i]          = f2bf(qkv1[k*576 + n]);
        ws[147456 + i] = f2bf(qkv2[k*576 + n]);
    }
    if (i < 36864) {
        const int n = i / 192, k = i - n*192;
        ws[110592 + i] = f2bf(proj1[k*192 + n]);
        ws[258048 + i] = f2bf(proj2[k*192 + n]);
    }
}

extern "C" void kernel_launch(void* const* d_in, const int* in_sizes, int n_in,
                              void* d_out, int out_size, void* d_ws, size_t ws_size,
                              hipStream_t stream)
{
    const float* x       = (const float*)d_in[0];
    const float* ln1_g   = (const float*)d_in[1];
    const float* ln1_b   = (const float*)d_in[2];
    const float* qkv1_w  = (const float*)d_in[3];
    const float* qkv1_b  = (const float*)d_in[4];
    const float* proj1_w = (const float*)d_in[5];
    const float* proj1_b = (const float*)d_in[6];
    const float* ln2_g   = (const float*)d_in[7];
    const float* ln2_b   = (const float*)d_in[8];
    const float* qkv2_w  = (const float*)d_in[9];
    const float* qkv2_b  = (const float*)d_in[10];
    const float* proj2_w = (const float*)d_in[11];
    const float* proj2_b = (const float*)d_in[12];
    float* out = (float*)d_out;
    u16*   wsp = (u16*)d_ws;

    prep_weights<<<dim3(432), dim3(256), 0, stream>>>(qkv1_w, proj1_w, qkv2_w, proj2_w, wsp);
    swin_branch<0><<<dim3(256), dim3(768), 0, stream>>>(x,   out, ln1_g, ln1_b,
                                                        wsp,        qkv1_b, wsp+110592, proj1_b);
    swin_branch<4><<<dim3(256), dim3(768), 0, stream>>>(out, out, ln2_g, ln2_b,
                                                        wsp+147456, qkv2_b, wsp+258048, proj2_b);
}

// Round 10
// 267.989 us; speedup vs baseline: 1.9124x; 1.9124x over previous
//
#include <hip/hip_runtime.h>

typedef unsigned int   u32;
typedef unsigned short u16;
typedef __bf16 bf16x8 __attribute__((ext_vector_type(8)));
typedef float  f32x4  __attribute__((ext_vector_type(4)));

__device__ __forceinline__ u16 f2bf(float f) {
    u32 u = __builtin_bit_cast(u32, f);
    u += 0x7FFFu + ((u >> 16) & 1u);
    return (u16)(u >> 16);
}
__device__ __forceinline__ u32 pk2bf(float a, float b) {
    return (u32)f2bf(a) | ((u32)f2bf(b) << 16);
}
__device__ __forceinline__ bf16x8 ldfrag(const u16* p) {
    return __builtin_bit_cast(bf16x8, *reinterpret_cast<const uint4*>(p));
}

// bank-conflict swizzle on the 16B-chunk index (0..63): fold bits[5:3] into [2:0].
__device__ __forceinline__ u32 swz(u32 i) { return i ^ ((i >> 3) & 7u); }

// ---------------------------------------------------------------------------
// Fused Swin branch: LN -> QKV -> windowed MHA -> proj -> +residual
// R7 structure (best: 176us/branch): WG = 768 threads = 12 waves = TWO
// independent windows -> balanced 3 waves/SIMD. R9's persistent-prefetch
// REVERTED (doubled HBM traffic, spilled).
// R10 changes, all inside phase 3's serial chain:
//   - softmax without max-subtraction (scores bounded: LN inputs x 0.02-scale
//     weights => |s|<~5; f32 exp safe); masked entries -> exact 0 via select.
//   - row-sum via ones-MFMA on the already-loaded P fragments (D rows align
//     with o_ rows) instead of 64 shfl_xor + adds.
//   - fast rcp for the normalization.
// Plus 2-pass QKV (q+k 16 acc -> one fewer yln read pass; v 8 acc).
// Per-window LDS partition (u16, base = win*24576):
//   [0,12288)      yln frag blocks; phase 3: wave w's own blocks {s*6+w} =
//                  scratch for k -> V^T -> attn_out (wave-local, DS in-order)
//   [12288,24576)  qreg per-head q A-frags; P staging reuses it after QK^T.
// ---------------------------------------------------------------------------
template<int SHIFT>
__global__ __launch_bounds__(768) void swin_branch(
    const float* __restrict__ xin, float* __restrict__ xout,
    const float* __restrict__ ln_g, const float* __restrict__ ln_b,
    const u16*   __restrict__ wqkv_t,  // [576][192] bf16 (pre-transposed)
    const float* __restrict__ qkv_b,   // [576]
    const u16*   __restrict__ wproj_t, // [192][192] bf16 (pre-transposed)
    const float* __restrict__ proj_b)  // [192]
{
    __shared__ __align__(16) u16 smem[49152];
    __shared__ float red1[2][6][64];
    __shared__ float red2[2][6][64];
    constexpr u32 QOFF = 12288;

    const int tid  = threadIdx.x;
    const int win  = (tid >= 384) ? 1 : 0;  // which of the WG's two windows
    const int lt   = tid - win*384;
    const int wid  = lt >> 6;               // wave == head
    const int lane = lt & 63;
    const int lr   = lane & 15;
    const int lg   = lane >> 4;
    const u32 lsw  = swz((u32)lane);        // read-side chunk index
    const u32 SB   = (u32)win * 24576u;     // per-window LDS base

    const int Wid = blockIdx.x*2 + win;     // b*256 + wy*16 + wx
    const int b   = Wid >> 8;
    const int wy  = (Wid >> 4) & 15;
    const int wx  = Wid & 15;

    // ---- Phase 1: gather window (rolled), LayerNorm -> yln (A-frag layout) ----
    {
        const int ty = lane >> 3, tx = lane & 7;
        const int shy = (wy*8 + ty + SHIFT) & 127;
        const int shx = (wx*8 + tx + SHIFT) & 127;
        const float* xp = xin + ((size_t)((b*128 + shy)*128 + shx))*192 + wid*32;
        float xv[32];
        float s1 = 0.f, s2 = 0.f;
        #pragma unroll
        for (int j = 0; j < 8; ++j) {
            float4 v = reinterpret_cast<const float4*>(xp)[j];
            xv[j*4+0]=v.x; xv[j*4+1]=v.y; xv[j*4+2]=v.z; xv[j*4+3]=v.w;
            s1 += v.x+v.y+v.z+v.w;
            s2 += v.x*v.x + v.y*v.y + v.z*v.z + v.w*v.w;
        }
        red1[win][wid][lane] = s1; red2[win][wid][lane] = s2;
        __syncthreads();
        float a1 = 0.f, a2 = 0.f;
        #pragma unroll
        for (int w = 0; w < 6; ++w) { a1 += red1[win][w][lane]; a2 += red2[win][w][lane]; }
        const float mu = a1 * (1.f/192.f);
        const float rs = rsqrtf(a2 * (1.f/192.f) - mu*mu + 1e-5f);
        const float* gp = ln_g + wid*32;
        const float* bp = ln_b + wid*32;
        const u32 yblk = SB + (u32)((lg*6 + wid)*512);
        #pragma unroll
        for (int cc8 = 0; cc8 < 4; ++cc8) {
            u32 pk[4];
            #pragma unroll
            for (int q = 0; q < 4; ++q) {
                int j = cc8*8 + q*2;
                float y0 = (xv[j]   - mu)*rs*gp[j]   + bp[j];
                float y1 = (xv[j+1] - mu)*rs*gp[j+1] + bp[j+1];
                pk[q] = pk2bf(y0, y1);
            }
            *reinterpret_cast<uint4*>(&smem[yblk + swz((u32)(lr + 16*cc8))*8]) =
                make_uint4(pk[0],pk[1],pk[2],pk[3]);
        }
    }
    __syncthreads();

    // ---- Phase 2: QKV GEMM, two passes (q+k: 16 acc; v: 8 acc) ----
    uint2 kpk[4][2];     // k packed bf16 (crosses barrier in regs)
    uint2 vpk[4][2];     // v packed bf16 (crosses barrier in regs)
    {
        // pass 1: q,k
        {
            f32x4 acc[4][4];
            #pragma unroll
            for (int mi=0; mi<4; ++mi)
                #pragma unroll
                for (int t=0; t<4; ++t) acc[mi][t] = f32x4{0.f,0.f,0.f,0.f};
            #pragma unroll
            for (int ks=0; ks<6; ++ks) {
                bf16x8 af[4];
                #pragma unroll
                for (int mi=0; mi<4; ++mi)
                    af[mi] = ldfrag(&smem[SB + (u32)((mi*6+ks)*512) + lsw*8]);
                bf16x8 bw[4];
                #pragma unroll
                for (int t=0; t<4; ++t)
                    bw[t] = ldfrag(&wqkv_t[((t>>1)*192 + wid*32 + (t&1)*16 + lr)*192 + 32*ks + 8*lg]);
                #pragma unroll
                for (int mi=0; mi<4; ++mi)
                    #pragma unroll
                    for (int t=0; t<4; ++t)
                        acc[mi][t] = __builtin_amdgcn_mfma_f32_16x16x32_bf16(af[mi], bw[t], acc[mi][t], 0,0,0);
            }
            // q: bias+scale -> qreg (wave-private, pre-barrier); k: bias -> kpk
            #pragma unroll
            for (int t=0; t<2; ++t) {
                const float bias = qkv_b[wid*32 + t*16 + lr];
                const u32 lphi   = (u32)(16*(2*t + (lr>>3)));
                #pragma unroll
                for (int mi=0; mi<4; ++mi)
                    #pragma unroll
                    for (int rg=0; rg<4; ++rg) {
                        const u32 pos = (u32)(4*lg + rg) + lphi;
                        smem[SB + QOFF + (u32)(wid*2048) + mi*512 + swz(pos)*8 + (lr&7)] =
                            f2bf((acc[mi][t][rg] + bias) * 0.1767766952966369f);
                    }
            }
            #pragma unroll
            for (int t2=0; t2<2; ++t2) {
                const float bias = qkv_b[192 + wid*32 + t2*16 + lr];
                #pragma unroll
                for (int mi=0; mi<4; ++mi)
                    kpk[mi][t2] = make_uint2(
                        pk2bf(acc[mi][2+t2][0] + bias, acc[mi][2+t2][1] + bias),
                        pk2bf(acc[mi][2+t2][2] + bias, acc[mi][2+t2][3] + bias));
            }
        }
        // pass 2: v
        {
            f32x4 acc[4][2];
            #pragma unroll
            for (int mi=0; mi<4; ++mi)
                #pragma unroll
                for (int t=0; t<2; ++t) acc[mi][t] = f32x4{0.f,0.f,0.f,0.f};
            #pragma unroll
            for (int ks=0; ks<6; ++ks) {
                bf16x8 af[4];
                #pragma unroll
                for (int mi=0; mi<4; ++mi)
                    af[mi] = ldfrag(&smem[SB + (u32)((mi*6+ks)*512) + lsw*8]);
                bf16x8 bw[2];
                #pragma unroll
                for (int t=0; t<2; ++t)
                    bw[t] = ldfrag(&wqkv_t[(384 + wid*32 + t*16 + lr)*192 + 32*ks + 8*lg]);
                #pragma unroll
                for (int mi=0; mi<4; ++mi)
                    #pragma unroll
                    for (int t=0; t<2; ++t)
                        acc[mi][t] = __builtin_amdgcn_mfma_f32_16x16x32_bf16(af[mi], bw[t], acc[mi][t], 0,0,0);
            }
            #pragma unroll
            for (int tv=0; tv<2; ++tv) {
                const float bias = qkv_b[384 + wid*32 + tv*16 + lr];
                #pragma unroll
                for (int mi=0; mi<4; ++mi)
                    vpk[mi][tv] = make_uint2(
                        pk2bf(acc[mi][tv][0] + bias, acc[mi][tv][1] + bias),
                        pk2bf(acc[mi][tv][2] + bias, acc[mi][tv][3] + bias));
            }
        }
    }
    __syncthreads();   // yln reads done -> wave w's blocks {s*6+w} become scratch

    // ---- Phase 3: attention, fully wave-local ----
    float rsum[4][4];
    f32x4 o_[4][2];
    {
        const u32 W  = SB + (u32)(wid*512);
        const u32 qb = SB + QOFF + (u32)(wid*2048);
        #define BLK(s) ((u32)(s)*3072u + W)

        // k scatter (from kpk) -> scratch blocks, read B-frags
        #pragma unroll
        for (int t2=0; t2<2; ++t2) {
            const u32 lphi = (u32)(16*(2*t2 + (lr>>3)));
            #pragma unroll
            for (int mi=0; mi<4; ++mi) {
                const u32 a0 = BLK(mi) + (lr&7);
                smem[a0 + swz((u32)(4*lg+0) + lphi)*8] = (u16)(kpk[mi][t2].x);
                smem[a0 + swz((u32)(4*lg+1) + lphi)*8] = (u16)(kpk[mi][t2].x >> 16);
                smem[a0 + swz((u32)(4*lg+2) + lphi)*8] = (u16)(kpk[mi][t2].y);
                smem[a0 + swz((u32)(4*lg+3) + lphi)*8] = (u16)(kpk[mi][t2].y >> 16);
            }
        }
        bf16x8 aq[4], bk[4];
        #pragma unroll
        for (int mi=0; mi<4; ++mi) aq[mi] = ldfrag(&smem[qb + mi*512 + lsw*8]);
        #pragma unroll
        for (int ni=0; ni<4; ++ni) bk[ni] = ldfrag(&smem[BLK(ni) + lsw*8]);
        __builtin_amdgcn_sched_barrier(0);

        // V^T scatter into same scratch (k dead after bk reads; DS in-order)
        #pragma unroll
        for (int tv=0; tv<2; ++tv)
            #pragma unroll
            for (int mi=0; mi<4; ++mi) {
                const u32 pos = (u32)(lr + 16*(2*(mi&1) + (lg>>1)));
                *reinterpret_cast<uint2*>(
                    &smem[BLK(tv*2 + (mi>>1)) + swz(pos)*8 + 4*(lg&1)]) = vpk[mi][tv];
            }

        // per-mi QK^T + exp (NO max-subtract: |s| bounded) + zero-mask
        int kl[4];
        if constexpr (SHIFT > 0) {
            #pragma unroll
            for (int ni=0; ni<4; ++ni) {
                const int col = 16*ni + lr;
                const int hu = wy*8 + (col>>3);
                const int wu = wx*8 + (col&7);
                kl[ni] = ((hu >= 124) ? 2 : (hu >= 120 ? 1 : 0))*3
                       + ((wu >= 124) ? 2 : (wu >= 120 ? 1 : 0));
            }
        }
        u32 p16[4][4][2];   // [mi][ni][rg-pair] unnormalized P in bf16 pairs
        #pragma unroll
        for (int mi=0; mi<4; ++mi) {
            f32x4 sr[4];
            #pragma unroll
            for (int ni=0; ni<4; ++ni)
                sr[ni] = __builtin_amdgcn_mfma_f32_16x16x32_bf16(aq[mi], bk[ni],
                             f32x4{0.f,0.f,0.f,0.f}, 0,0,0);
            #pragma unroll
            for (int rg=0; rg<4; ++rg) {
                int rl = 0;
                if constexpr (SHIFT > 0) {
                    const int row = 16*mi + 4*lg + rg;
                    const int hu = wy*8 + (row>>3);
                    const int wu = wx*8 + (row&7);
                    rl = ((hu >= 124) ? 2 : (hu >= 120 ? 1 : 0))*3
                       + ((wu >= 124) ? 2 : (wu >= 120 ? 1 : 0));
                }
                #pragma unroll
                for (int ni=0; ni<4; ++ni) {
                    float e = __expf(sr[ni][rg]);
                    if constexpr (SHIFT > 0)
                        e = (rl == kl[ni]) ? e : 0.f;
                    sr[ni][rg] = e;
                }
            }
            #pragma unroll
            for (int ni=0; ni<4; ++ni) {
                p16[mi][ni][0] = pk2bf(sr[ni][0], sr[ni][1]);
                p16[mi][ni][1] = pk2bf(sr[ni][2], sr[ni][3]);
            }
        }

        // P staged in two ksv halves in qreg (q dead after QK^T); frags to regs
        bf16x8 ap0[4], ap1[4];
        #pragma unroll
        for (int mi=0; mi<4; ++mi)
            #pragma unroll
            for (int ni=0; ni<2; ++ni)
                #pragma unroll
                for (int rg=0; rg<4; ++rg) {
                    const u32 pos = (u32)(4*lg + rg + 16*(2*ni + (lr>>3)));
                    smem[qb + mi*512 + swz(pos)*8 + (lr&7)] =
                        (u16)(p16[mi][ni][rg>>1] >> (16*(rg&1)));
                }
        #pragma unroll
        for (int mi=0; mi<4; ++mi) ap0[mi] = ldfrag(&smem[qb + mi*512 + lsw*8]);
        __builtin_amdgcn_sched_barrier(0);
        #pragma unroll
        for (int mi=0; mi<4; ++mi)
            #pragma unroll
            for (int ni=2; ni<4; ++ni)
                #pragma unroll
                for (int rg=0; rg<4; ++rg) {
                    const u32 pos = (u32)(4*lg + rg + 16*(2*(ni-2) + (lr>>3)));
                    smem[qb + mi*512 + swz(pos)*8 + (lr&7)] =
                        (u16)(p16[mi][ni][rg>>1] >> (16*(rg&1)));
                }
        #pragma unroll
        for (int mi=0; mi<4; ++mi) ap1[mi] = ldfrag(&smem[qb + mi*512 + lsw*8]);
        __builtin_amdgcn_sched_barrier(0);

        // row sums via ones-MFMA on the P fragments (D rows == o_ rows)
        bf16x8 vones;
        #pragma unroll
        for (int j=0; j<8; ++j) vones[j] = (__bf16)1.0f;
        #pragma unroll
        for (int mi=0; mi<4; ++mi) {
            f32x4 racc = __builtin_amdgcn_mfma_f32_16x16x32_bf16(ap0[mi], vones,
                             f32x4{0.f,0.f,0.f,0.f}, 0,0,0);
            racc = __builtin_amdgcn_mfma_f32_16x16x32_bf16(ap1[mi], vones, racc, 0,0,0);
            #pragma unroll
            for (int rg=0; rg<4; ++rg)
                rsum[mi][rg] = __builtin_amdgcn_rcpf(racc[rg]);
        }

        bf16x8 bv[2][2];
        #pragma unroll
        for (int tv=0; tv<2; ++tv)
            #pragma unroll
            for (int ksv=0; ksv<2; ++ksv)
                bv[tv][ksv] = ldfrag(&smem[BLK(tv*2+ksv) + lsw*8]);

        // PV
        #pragma unroll
        for (int mi=0; mi<4; ++mi)
            #pragma unroll
            for (int tv=0; tv<2; ++tv) {
                o_[mi][tv] = __builtin_amdgcn_mfma_f32_16x16x32_bf16(ap0[mi], bv[tv][0],
                                 f32x4{0.f,0.f,0.f,0.f}, 0,0,0);
                o_[mi][tv] = __builtin_amdgcn_mfma_f32_16x16x32_bf16(ap1[mi], bv[tv][1],
                                 o_[mi][tv], 0,0,0);
            }
        __builtin_amdgcn_sched_barrier(0);

        // normalized attn_out -> own scratch blocks (= proj A-frag blocks ks=wid)
        #pragma unroll
        for (int mi=0; mi<4; ++mi)
            #pragma unroll
            for (int tv=0; tv<2; ++tv)
                #pragma unroll
                for (int rg=0; rg<4; ++rg) {
                    const u32 pos = (u32)(4*lg + rg + 16*(2*tv + (lr>>3)));
                    smem[BLK(mi) + swz(pos)*8 + (lr&7)] = f2bf(o_[mi][tv][rg] * rsum[mi][rg]);
                }
        #undef BLK
    }
    __syncthreads();

    // ---- Phase 4: proj GEMM [64x192]@[192x192] + bias + residual ----
    {
        f32x4 a2[4][2];
        #pragma unroll
        for (int mi=0; mi<4; ++mi)
            #pragma unroll
            for (int ni=0; ni<2; ++ni) a2[mi][ni] = f32x4{0.f,0.f,0.f,0.f};
        #pragma unroll
        for (int ks=0; ks<6; ++ks) {
            bf16x8 af[4], bw[2];
            #pragma unroll
            for (int mi=0; mi<4; ++mi)
                af[mi] = ldfrag(&smem[SB + (u32)((mi*6+ks)*512) + lsw*8]);
            #pragma unroll
            for (int ni=0; ni<2; ++ni)
                bw[ni] = ldfrag(&wproj_t[(wid*32 + 16*ni + lr)*192 + 32*ks + 8*lg]);
            #pragma unroll
            for (int mi=0; mi<4; ++mi)
                #pragma unroll
                for (int ni=0; ni<2; ++ni)
                    a2[mi][ni] = __builtin_amdgcn_mfma_f32_16x16x32_bf16(af[mi], bw[ni], a2[mi][ni], 0,0,0);
        }
        #pragma unroll
        for (int ni=0; ni<2; ++ni) {
            const int c  = wid*32 + 16*ni + lr;
            const float pb = proj_b[c];
            #pragma unroll
            for (int mi=0; mi<4; ++mi)
                #pragma unroll
                for (int rg=0; rg<4; ++rg) {
                    const int row = 16*mi + 4*lg + rg;
                    const int ty = row >> 3, tx = row & 7;
                    const int shy = (wy*8 + ty + SHIFT) & 127;
                    const int shx = (wx*8 + tx + SHIFT) & 127;
                    const size_t idx = ((size_t)((b*128 + shy)*128 + shx))*192 + c;
                    xout[idx] = xin[idx] + a2[mi][ni][rg] + pb;
                }
        }
    }
}

// ws layout (u16): [0) wqkv1_t 110592 | 110592) wproj1_t 36864 | 147456) wqkv2_t 110592 | 258048) wproj2_t 36864
__global__ void prep_weights(const float* __restrict__ qkv1, const float* __restrict__ proj1,
                             const float* __restrict__ qkv2, const float* __restrict__ proj2,
                             u16* __restrict__ ws)
{
    const int i = blockIdx.x*blockDim.x + threadIdx.x;
    if (i < 110592) {
        const int n = i / 192, k = i - n*192;
        ws[i]          = f2bf(qkv1[k*576 + n]);
        ws[147456 + i] = f2bf(qkv2[k*576 + n]);
    }
    if (i < 36864) {
        const int n = i / 192, k = i - n*192;
        ws[110592 + i] = f2bf(proj1[k*192 + n]);
        ws[258048 + i] = f2bf(proj2[k*192 + n]);
    }
}

extern "C" void kernel_launch(void* const* d_in, const int* in_sizes, int n_in,
                              void* d_out, int out_size, void* d_ws, size_t ws_size,
                              hipStream_t stream)
{
    const float* x       = (const float*)d_in[0];
    const float* ln1_g   = (const float*)d_in[1];
    const float* ln1_b   = (const float*)d_in[2];
    const float* qkv1_w  = (const float*)d_in[3];
    const float* qkv1_b  = (const float*)d_in[4];
    const float* proj1_w = (const float*)d_in[5];
    const float* proj1_b = (const float*)d_in[6];
    const float* ln2_g   = (const float*)d_in[7];
    const float* ln2_b   = (const float*)d_in[8];
    const float* qkv2_w  = (const float*)d_in[9];
    const float* qkv2_b  = (const float*)d_in[10];
    const float* proj2_w = (const float*)d_in[11];
    const float* proj2_b = (const float*)d_in[12];
    float* out = (float*)d_out;
    u16*   wsp = (u16*)d_ws;

    prep_weights<<<dim3(432), dim3(256), 0, stream>>>(qkv1_w, proj1_w, qkv2_w, proj2_w, wsp);
    swin_branch<0><<<dim3(1024), dim3(768), 0, stream>>>(x,   out, ln1_g, ln1_b,
                                                         wsp,        qkv1_b, wsp+110592, proj1_b);
    swin_branch<4><<<dim3(1024), dim3(768), 0, stream>>>(out, out, ln2_g, ln2_b,
                                                         wsp+147456, qkv2_b, wsp+258048, proj2_b);
}

// Round 12
// 262.831 us; speedup vs baseline: 1.9499x; 1.0196x over previous
//
#include <hip/hip_runtime.h>

typedef unsigned int   u32;
typedef unsigned short u16;
typedef __bf16 bf16x8 __attribute__((ext_vector_type(8)));
typedef float  f32x4  __attribute__((ext_vector_type(4)));

__device__ __forceinline__ u16 f2bf(float f) {
    u32 u = __builtin_bit_cast(u32, f);
    u += 0x7FFFu + ((u >> 16) & 1u);
    return (u16)(u >> 16);
}
// packed f32x2 -> bf16x2 (RNE), single instruction
__device__ __forceinline__ u32 cvtpk(float a, float b) {
    u32 r;
    asm("v_cvt_pk_bf16_f32 %0, %1, %2" : "=v"(r) : "v"(a), "v"(b));
    return r;
}
__device__ __forceinline__ bf16x8 ldfrag(const u16* p) {
    return __builtin_bit_cast(bf16x8, *reinterpret_cast<const uint4*>(p));
}

// bank-conflict swizzle on the 16B-chunk index (0..63): fold bits[5:3] into [2:0].
__device__ __forceinline__ u32 swz(u32 i) { return i ^ ((i >> 3) & 7u); }

// ---------------------------------------------------------------------------
// Fused Swin branch, R11/R12: operand-SWAPPED dataflow so every LDS scatter is
// a vectorized ds_write_b64.
//   - A-frag and B-frag share the chunk formula (chunk = idx&15 + 16*(k>>3),
//     j=k&7), so yln serves as either operand and W loads are identical.
//   - q/k passes compute Q^T,K^T = mfma(W, yln) (swapped args): D puts dim on
//     4lg+rg, token on lr -> scatters of Q(B-frag), K(A-frag) have j=4(lg&1)+rg
//     consecutive, fixed chunk -> uint2 writes.
//   - QK swapped: S^T = mfma(K,Q); softmax per q-col is lane-local on lr
//     (rsum: 4 regs); P^T scatter + O^T=mfma(V^T,P^T) + attn-out scatter all
//     uint2. P uses all 8 free scratch blocks at once (single staging step).
//   - v_cvt_pk_bf16_f32 for all hot f32->bf16; exp2f with log2e folded into
//     the q-scale (v_exp_f32 computes 2^x natively).
// WG = 768 threads = 12 waves = TWO windows (R7 balanced placement).
// Per-window LDS (u16, base=win*24576): [0,12288) yln 24 frag blocks
// (phase 3: wave w's blocks {s*6+w} = K scratch -> P(ks=1) -> O^T);
// [12288,24576) qreg 4 blocks/head (Q -> P(ks=0) -> V^T).
// ---------------------------------------------------------------------------
template<int SHIFT>
__global__ __launch_bounds__(768) void swin_branch(
    const float* __restrict__ xin, float* __restrict__ xout,
    const float* __restrict__ ln_g, const float* __restrict__ ln_b,
    const u16*   __restrict__ wqkv_t,  // [576][192] bf16 (pre-transposed)
    const float* __restrict__ qkv_b,   // [576]
    const u16*   __restrict__ wproj_t, // [192][192] bf16 (pre-transposed)
    const float* __restrict__ proj_b)  // [192]
{
    __shared__ __align__(16) u16 smem[49152];
    __shared__ float red1[2][6][64];
    __shared__ float red2[2][6][64];
    constexpr u32 QOFF = 12288;
    constexpr float QSC = 0.17677669529663689f * 1.4426950408889634f; // 1/sqrt(32)*log2(e)

    const int tid  = threadIdx.x;
    const int win  = (tid >= 384) ? 1 : 0;
    const int lt   = tid - win*384;
    const int wid  = lt >> 6;               // wave == head
    const int lane = lt & 63;
    const int lr   = lane & 15;
    const int lg   = lane >> 4;
    const u32 lsw  = swz((u32)lane);
    const u32 SB   = (u32)win * 24576u;

    const int Wid = blockIdx.x*2 + win;     // b*256 + wy*16 + wx
    const int b   = Wid >> 8;
    const int wy  = (Wid >> 4) & 15;
    const int wx  = Wid & 15;

    // ---- Phase 1: gather window (rolled), LayerNorm -> yln (frag layout) ----
    {
        const int ty = lane >> 3, tx = lane & 7;
        const int shy = (wy*8 + ty + SHIFT) & 127;
        const int shx = (wx*8 + tx + SHIFT) & 127;
        const float* xp = xin + ((size_t)((b*128 + shy)*128 + shx))*192 + wid*32;
        float xv[32];
        float s1 = 0.f, s2 = 0.f;
        #pragma unroll
        for (int j = 0; j < 8; ++j) {
            float4 v = reinterpret_cast<const float4*>(xp)[j];
            xv[j*4+0]=v.x; xv[j*4+1]=v.y; xv[j*4+2]=v.z; xv[j*4+3]=v.w;
            s1 += v.x+v.y+v.z+v.w;
            s2 += v.x*v.x + v.y*v.y + v.z*v.z + v.w*v.w;
        }
        red1[win][wid][lane] = s1; red2[win][wid][lane] = s2;
        __syncthreads();
        float a1 = 0.f, a2 = 0.f;
        #pragma unroll
        for (int w = 0; w < 6; ++w) { a1 += red1[win][w][lane]; a2 += red2[win][w][lane]; }
        const float mu = a1 * (1.f/192.f);
        const float rs = rsqrtf(a2 * (1.f/192.f) - mu*mu + 1e-5f);
        const float* gp = ln_g + wid*32;
        const float* bp = ln_b + wid*32;
        const u32 yblk = SB + (u32)((lg*6 + wid)*512);
        #pragma unroll
        for (int cc8 = 0; cc8 < 4; ++cc8) {
            u32 pk[4];
            #pragma unroll
            for (int q = 0; q < 4; ++q) {
                int j = cc8*8 + q*2;
                float y0 = (xv[j]   - mu)*rs*gp[j]   + bp[j];
                float y1 = (xv[j+1] - mu)*rs*gp[j+1] + bp[j+1];
                pk[q] = cvtpk(y0, y1);
            }
            *reinterpret_cast<uint4*>(&smem[yblk + swz((u32)(lr + 16*cc8))*8]) =
                make_uint4(pk[0],pk[1],pk[2],pk[3]);
        }
    }
    __syncthreads();

    // ---- Phase 2: QKV GEMM ----
    uint2 kpk[4][2];     // K^T packed bf16 (crosses barrier in regs)
    uint2 vpk[4][2];     // V  packed bf16 (crosses barrier in regs)
    {
        // pass 1 (SWAPPED): Q^T,K^T = mfma(W-frag, yln-frag)
        // D: lane holds X^T[d=16t+4lg+rg][token=16mi+lr]
        {
            f32x4 acc[4][4];
            #pragma unroll
            for (int mi=0; mi<4; ++mi)
                #pragma unroll
                for (int t=0; t<4; ++t) acc[mi][t] = f32x4{0.f,0.f,0.f,0.f};
            #pragma unroll
            for (int ks=0; ks<6; ++ks) {
                bf16x8 af[4];
                #pragma unroll
                for (int mi=0; mi<4; ++mi)
                    af[mi] = ldfrag(&smem[SB + (u32)((mi*6+ks)*512) + lsw*8]);
                bf16x8 bw[4];
                #pragma unroll
                for (int t=0; t<4; ++t)
                    bw[t] = ldfrag(&wqkv_t[((t>>1)*192 + wid*32 + (t&1)*16 + lr)*192 + 32*ks + 8*lg]);
                #pragma unroll
                for (int mi=0; mi<4; ++mi)
                    #pragma unroll
                    for (int t=0; t<4; ++t)
                        acc[mi][t] = __builtin_amdgcn_mfma_f32_16x16x32_bf16(bw[t], af[mi], acc[mi][t], 0,0,0);
            }
            // Q: bias + QSC scale -> qreg as B-frag (uint2 writes, wave-private)
            #pragma unroll
            for (int t=0; t<2; ++t) {
                const float4 b4 = *reinterpret_cast<const float4*>(&qkv_b[wid*32 + t*16 + 4*lg]);
                const u32 chunk = (u32)lr + 16u*(u32)(2*t + (lg>>1));
                #pragma unroll
                for (int mi=0; mi<4; ++mi) {
                    float v0 = (acc[mi][t][0] + b4.x) * QSC;
                    float v1 = (acc[mi][t][1] + b4.y) * QSC;
                    float v2 = (acc[mi][t][2] + b4.z) * QSC;
                    float v3 = (acc[mi][t][3] + b4.w) * QSC;
                    *reinterpret_cast<uint2*>(
                        &smem[SB + QOFF + (u32)(wid*2048) + mi*512 + swz(chunk)*8 + 4*(lg&1)]) =
                        make_uint2(cvtpk(v0,v1), cvtpk(v2,v3));
                }
            }
            // K: bias -> kpk regs
            #pragma unroll
            for (int t2=0; t2<2; ++t2) {
                const float4 b4 = *reinterpret_cast<const float4*>(&qkv_b[192 + wid*32 + t2*16 + 4*lg]);
                #pragma unroll
                for (int mi=0; mi<4; ++mi)
                    kpk[mi][t2] = make_uint2(
                        cvtpk(acc[mi][2+t2][0] + b4.x, acc[mi][2+t2][1] + b4.y),
                        cvtpk(acc[mi][2+t2][2] + b4.z, acc[mi][2+t2][3] + b4.w));
            }
        }
        // pass 2 (unswapped): V = mfma(yln, Wv); lane holds V[token=16mi+4lg+rg][d=16tv+lr]
        {
            f32x4 acc[4][2];
            #pragma unroll
            for (int mi=0; mi<4; ++mi)
                #pragma unroll
                for (int t=0; t<2; ++t) acc[mi][t] = f32x4{0.f,0.f,0.f,0.f};
            #pragma unroll
            for (int ks=0; ks<6; ++ks) {
                bf16x8 af[4];
                #pragma unroll
                for (int mi=0; mi<4; ++mi)
                    af[mi] = ldfrag(&smem[SB + (u32)((mi*6+ks)*512) + lsw*8]);
                bf16x8 bw[2];
                #pragma unroll
                for (int t=0; t<2; ++t)
                    bw[t] = ldfrag(&wqkv_t[(384 + wid*32 + t*16 + lr)*192 + 32*ks + 8*lg]);
                #pragma unroll
                for (int mi=0; mi<4; ++mi)
                    #pragma unroll
                    for (int t=0; t<2; ++t)
                        acc[mi][t] = __builtin_amdgcn_mfma_f32_16x16x32_bf16(af[mi], bw[t], acc[mi][t], 0,0,0);
            }
            #pragma unroll
            for (int tv=0; tv<2; ++tv) {
                const float bias = qkv_b[384 + wid*32 + tv*16 + lr];
                #pragma unroll
                for (int mi=0; mi<4; ++mi)
                    vpk[mi][tv] = make_uint2(
                        cvtpk(acc[mi][tv][0] + bias, acc[mi][tv][1] + bias),
                        cvtpk(acc[mi][tv][2] + bias, acc[mi][tv][3] + bias));
            }
        }
    }
    __syncthreads();   // yln reads done -> wave w's blocks {s*6+w} become scratch

    // ---- Phase 3: attention (all-swapped, wave-local) ----
    float rsum[4];       // per q-col tile nq (q is lane-local on lr)
    f32x4 o_[2][4];      // O^T [dv][nq]
    {
        const u32 W  = SB + (u32)(wid*512);
        const u32 QB = SB + QOFF + (u32)(wid*2048);
        #define BLK(s) ((u32)(s)*3072u + W)

        // K scatter (A-frag): block mi, chunk = lr + 16*(2t2+(lg>>1))
        #pragma unroll
        for (int t2=0; t2<2; ++t2) {
            const u32 chunk = (u32)lr + 16u*(u32)(2*t2 + (lg>>1));
            #pragma unroll
            for (int mi=0; mi<4; ++mi)
                *reinterpret_cast<uint2*>(
                    &smem[BLK(mi) + swz(chunk)*8 + 4*(lg&1)]) = kpk[mi][t2];
        }
        bf16x8 ak[4], bq[4];
        #pragma unroll
        for (int mi=0; mi<4; ++mi) ak[mi] = ldfrag(&smem[BLK(mi) + lsw*8]);
        #pragma unroll
        for (int nq=0; nq<4; ++nq) bq[nq] = ldfrag(&smem[QB + nq*512 + lsw*8]);
        __builtin_amdgcn_sched_barrier(0);

        // q-col classes (per nq; col qt = 16nq+lr)
        int qcl[4];
        if constexpr (SHIFT > 0) {
            #pragma unroll
            for (int nq=0; nq<4; ++nq) {
                const int qt = 16*nq + lr;
                const int hu = wy*8 + (qt>>3);
                const int wu = wx*8 + (qt&7);
                qcl[nq] = ((hu >= 124) ? 2 : (hu >= 120 ? 1 : 0))*3
                        + ((wu >= 124) ? 2 : (wu >= 120 ? 1 : 0));
            }
        }

        // S^T = mfma(K,Q); exp2 (q pre-scaled by log2e/sqrt(d)); zero-mask; pack
        uint2 p16[4][4];    // [mi][nq]
        #pragma unroll
        for (int mi=0; mi<4; ++mi) {
            f32x4 sr[4];
            #pragma unroll
            for (int nq=0; nq<4; ++nq)
                sr[nq] = __builtin_amdgcn_mfma_f32_16x16x32_bf16(ak[mi], bq[nq],
                             f32x4{0.f,0.f,0.f,0.f}, 0,0,0);
            #pragma unroll
            for (int rg=0; rg<4; ++rg) {
                int kcl = 0;
                if constexpr (SHIFT > 0) {
                    const int kt = 16*mi + 4*lg + rg;
                    const int hu = wy*8 + (kt>>3);
                    const int wu = wx*8 + (kt&7);
                    kcl = ((hu >= 124) ? 2 : (hu >= 120 ? 1 : 0))*3
                        + ((wu >= 124) ? 2 : (wu >= 120 ? 1 : 0));
                }
                #pragma unroll
                for (int nq=0; nq<4; ++nq) {
                    float e = exp2f(sr[nq][rg]);
                    if constexpr (SHIFT > 0)
                        e = (kcl == qcl[nq]) ? e : 0.f;
                    sr[nq][rg] = e;
                }
            }
            #pragma unroll
            for (int nq=0; nq<4; ++nq)
                p16[mi][nq] = make_uint2(cvtpk(sr[nq][0], sr[nq][1]),
                                         cvtpk(sr[nq][2], sr[nq][3]));
        }

        // P^T scatter (B-frag): block(nq, ks=mi>>1): ks0 -> QB(nq), ks1 -> BLK(nq)
        #pragma unroll
        for (int mi=0; mi<4; ++mi) {
            const u32 chunk = (u32)lr + 16u*(u32)(2*(mi&1) + (lg>>1));
            #pragma unroll
            for (int nq=0; nq<4; ++nq) {
                const u32 base = (mi >> 1) ? BLK(nq) : (QB + nq*512);
                *reinterpret_cast<uint2*>(&smem[base + swz(chunk)*8 + 4*(lg&1)]) = p16[mi][nq];
            }
        }
        bf16x8 bp[4][2];
        #pragma unroll
        for (int nq=0; nq<4; ++nq) {
            bp[nq][0] = ldfrag(&smem[QB + nq*512 + lsw*8]);
            bp[nq][1] = ldfrag(&smem[BLK(nq) + lsw*8]);
        }
        __builtin_amdgcn_sched_barrier(0);

        // row sums per q-col via ones-MFMA on P^T B-frags
        bf16x8 aones;
        {
            const u32 one2 = 0x3F803F80u;
            aones = __builtin_bit_cast(bf16x8, make_uint4(one2, one2, one2, one2));
        }
        #pragma unroll
        for (int nq=0; nq<4; ++nq) {
            f32x4 racc = __builtin_amdgcn_mfma_f32_16x16x32_bf16(aones, bp[nq][0],
                             f32x4{0.f,0.f,0.f,0.f}, 0,0,0);
            racc = __builtin_amdgcn_mfma_f32_16x16x32_bf16(aones, bp[nq][1], racc, 0,0,0);
            rsum[nq] = __builtin_amdgcn_rcpf(racc[0]);
        }

        // V^T scatter (A-frag) into QB blocks (P ks=0 dead after bp reads)
        #pragma unroll
        for (int mi=0; mi<4; ++mi) {
            const u32 chunk = (u32)lr + 16u*(u32)(2*(mi&1) + (lg>>1));
            #pragma unroll
            for (int tv=0; tv<2; ++tv)
                *reinterpret_cast<uint2*>(
                    &smem[QB + (u32)((2*tv + (mi>>1))*512) + swz(chunk)*8 + 4*(lg&1)]) = vpk[mi][tv];
        }
        bf16x8 av[2][2];
        #pragma unroll
        for (int dv=0; dv<2; ++dv)
            #pragma unroll
            for (int ks=0; ks<2; ++ks)
                av[dv][ks] = ldfrag(&smem[QB + (u32)((2*dv + ks)*512) + lsw*8]);
        __builtin_amdgcn_sched_barrier(0);

        // O^T = V^T * P^T
        #pragma unroll
        for (int dv=0; dv<2; ++dv)
            #pragma unroll
            for (int nq=0; nq<4; ++nq) {
                o_[dv][nq] = __builtin_amdgcn_mfma_f32_16x16x32_bf16(av[dv][0], bp[nq][0],
                                 f32x4{0.f,0.f,0.f,0.f}, 0,0,0);
                o_[dv][nq] = __builtin_amdgcn_mfma_f32_16x16x32_bf16(av[dv][1], bp[nq][1],
                                 o_[dv][nq], 0,0,0);
            }
        __builtin_amdgcn_sched_barrier(0);

        // normalized attn_out -> proj A-frag blocks BLK(nq) (uint2 writes)
        #pragma unroll
        for (int dv=0; dv<2; ++dv) {
            const u32 chunk = (u32)lr + 16u*(u32)(2*dv + (lg>>1));
            #pragma unroll
            for (int nq=0; nq<4; ++nq) {
                const float r = rsum[nq];
                *reinterpret_cast<uint2*>(&smem[BLK(nq) + swz(chunk)*8 + 4*(lg&1)]) =
                    make_uint2(cvtpk(o_[dv][nq][0]*r, o_[dv][nq][1]*r),
                               cvtpk(o_[dv][nq][2]*r, o_[dv][nq][3]*r));
            }
        }
        #undef BLK
    }
    __syncthreads();

    // ---- Phase 4: proj GEMM [64x192]@[192x192] + bias + residual ----
    {
        f32x4 a2[4][2];
        #pragma unroll
        for (int mi=0; mi<4; ++mi)
            #pragma unroll
            for (int ni=0; ni<2; ++ni) a2[mi][ni] = f32x4{0.f,0.f,0.f,0.f};
        #pragma unroll
        for (int ks=0; ks<6; ++ks) {
            bf16x8 af[4], bw[2];
            #pragma unroll
            for (int mi=0; mi<4; ++mi)
                af[mi] = ldfrag(&smem[SB + (u32)((mi*6+ks)*512) + lsw*8]);
            #pragma unroll
            for (int ni=0; ni<2; ++ni)
                bw[ni] = ldfrag(&wproj_t[(wid*32 + 16*ni + lr)*192 + 32*ks + 8*lg]);
            #pragma unroll
            for (int mi=0; mi<4; ++mi)
                #pragma unroll
                for (int ni=0; ni<2; ++ni)
                    a2[mi][ni] = __builtin_amdgcn_mfma_f32_16x16x32_bf16(af[mi], bw[ni], a2[mi][ni], 0,0,0);
        }
        #pragma unroll
        for (int ni=0; ni<2; ++ni) {
            const int c  = wid*32 + 16*ni + lr;
            const float pb = proj_b[c];
            #pragma unroll
            for (int mi=0; mi<4; ++mi)
                #pragma unroll
                for (int rg=0; rg<4; ++rg) {
                    const int row = 16*mi + 4*lg + rg;
                    const int ty = row >> 3, tx = row & 7;
                    const int shy = (wy*8 + ty + SHIFT) & 127;
                    const int shx = (wx*8 + tx + SHIFT) & 127;
                    const size_t idx = ((size_t)((b*128 + shy)*128 + shx))*192 + c;
                    xout[idx] = xin[idx] + a2[mi][ni][rg] + pb;
                }
        }
    }
}

// ws layout (u16): [0) wqkv1_t 110592 | 110592) wproj1_t 36864 | 147456) wqkv2_t 110592 | 258048) wproj2_t 36864
__global__ void prep_weights(const float* __restrict__ qkv1, const float* __restrict__ proj1,
                             const float* __restrict__ qkv2, const float* __restrict__ proj2,
                             u16* __restrict__ ws)
{
    const int i = blockIdx.x*blockDim.x + threadIdx.x;
    if (i < 110592) {
        const int n = i / 192, k = i - n*192;
        ws[i]          = f2bf(qkv1[k*576 + n]);
        ws[147456 + i] = f2bf(qkv2[k*576 + n]);
    }
    if (i < 36864) {
        const int n = i / 192, k = i - n*192;
        ws[110592 + i] = f2bf(proj1[k*192 + n]);
        ws[258048 + i] = f2bf(proj2[k*192 + n]);
    }
}

extern "C" void kernel_launch(void* const* d_in, const int* in_sizes, int n_in,
                              void* d_out, int out_size, void* d_ws, size_t ws_size,
                              hipStream_t stream)
{
    const float* x       = (const float*)d_in[0];
    const float* ln1_g   = (const float*)d_in[1];
    const float* ln1_b   = (const float*)d_in[2];
    const float* qkv1_w  = (const float*)d_in[3];
    const float* qkv1_b  = (const float*)d_in[4];
    const float* proj1_w = (const float*)d_in[5];
    const float* proj1_b = (const float*)d_in[6];
    const float* ln2_g   = (const float*)d_in[7];
    const float* ln2_b   = (const float*)d_in[8];
    const float* qkv2_w  = (const float*)d_in[9];
    const float* qkv2_b  = (const float*)d_in[10];
    const float* proj2_w = (const float*)d_in[11];
    const float* proj2_b = (const float*)d_in[12];
    float* out = (float*)d_out;
    u16*   wsp = (u16*)d_ws;

    prep_weights<<<dim3(432), dim3(256), 0, stream>>>(qkv1_w, proj1_w, qkv2_w, proj2_w, wsp);
    swin_branch<0><<<dim3(1024), dim3(768), 0, stream>>>(x,   out, ln1_g, ln1_b,
                                                         wsp,        qkv1_b, wsp+110592, proj1_b);
    swin_branch<4><<<dim3(1024), dim3(768), 0, stream>>>(out, out, ln2_g, ln2_b,
                                                         wsp+147456, qkv2_b, wsp+258048, proj2_b);
}